// Round 7
// baseline (543.273 us; speedup 1.0000x reference)
//
#include <hip/hip_runtime.h>
#include <math.h>

#define B 1024
#define NV 6890
#define NP 207
#define KP 224      // padded K (207 pf + 10 betas + 7 zero)
#define NR 20736    // padded comp rows (108*192)
#define VT 64       // verts per tile
#define BT 16       // batches per tile

typedef float fx2 __attribute__((ext_vector_type(2)));
typedef float fx4 __attribute__((ext_vector_type(4)));
typedef short s8v __attribute__((ext_vector_type(8)));   // 8 bf16 (MFMA A/B frag)
typedef float f4v __attribute__((ext_vector_type(4)));   // MFMA C/D frag

// ---- output layout (floats) ----
#define OFF_J   21166080
#define OFF_J17 21239808
#define OFF_R   21292032

// ---- workspace layout (byte offsets) ----
#define WSB_A    0           // [1024][288] f32   1,179,648
#define WSB_JRX  1179648     // [72][11] f32      3,168
#define WSB_PF32 1183744     // [1024][208] f32   851,968  (ends 2,035,712)
#define WSB_PFB  2035712     // [1024][224] bf16  458,752  (big path only)
#define WSB_PDT  2494464     // [CH][224] bf16    chunk-sized (big path only)

__device__ __constant__ int PAR[24] = {0,0,0,0,1,2,3,4,5,6,7,8,9,9,9,12,13,14,16,17,18,19,20,21};

__device__ inline unsigned short f2bf(float f) {
  unsigned int u = __builtin_bit_cast(unsigned int, f);
  unsigned int r = (u + 0x7FFFu + ((u >> 16) & 1u)) >> 16;
  return (unsigned short)r;
}

// K0: JRX[(j*3+c)*11 + l] = sum_v JR[j,v] * (l==0 ? v_template[v,c] : shapedirs[v,c,l-1])
__global__ __launch_bounds__(256) void k_jrx(const float* __restrict__ JR,
    const float* __restrict__ vtm, const float* __restrict__ sd,
    float* __restrict__ JRX) {
  int o = blockIdx.x;
  int j = o / 3, c = o % 3;
  float acc[11];
#pragma unroll
  for (int q = 0; q < 11; q++) acc[q] = 0.f;
  for (int v = threadIdx.x; v < NV; v += 256) {
    float r = JR[(size_t)j * NV + v];
    acc[0] += r * vtm[(size_t)v * 3 + c];
    const float* s = sd + (size_t)v * 30 + c * 10;
#pragma unroll
    for (int l = 0; l < 10; l++) acc[1 + l] += r * s[l];
  }
#pragma unroll
  for (int q = 0; q < 11; q++) {
    for (int off = 32; off; off >>= 1) acc[q] += __shfl_xor(acc[q], off, 64);
  }
  __shared__ float red[4][11];
  int wave = threadIdx.x >> 6, lane = threadIdx.x & 63;
  if (lane == 0) {
#pragma unroll
    for (int q = 0; q < 11; q++) red[wave][q] = acc[q];
  }
  __syncthreads();
  if (threadIdx.x < 11) {
    int q = threadIdx.x;
    JRX[o * 11 + q] = red[0][q] + red[1][q] + red[2][q] + red[3][q];
  }
}

// K1: rodrigues, pf (f32 + optional bf16), joints, chain, A
__global__ __launch_bounds__(128) void k_pose(const float* __restrict__ go,
    const float* __restrict__ paa, const float* __restrict__ betas,
    const float* __restrict__ JRX, float* __restrict__ rot_out,
    float* __restrict__ joints_out, float* __restrict__ pf32,
    unsigned short* __restrict__ pfb, float* __restrict__ A, int write_pfb) {
  int b = blockIdx.x, t = threadIdx.x;
  __shared__ float Rl[24][9];
  __shared__ float Jl[24][3];
  __shared__ float Cl[24][12];
  __shared__ float pfl[KP];

  for (int i = t; i < KP; i += 128) pfl[i] = 0.f;
  __syncthreads();

  if (t < 24) {
    float x, y, z;
    if (t == 0) { x = go[b*3]; y = go[b*3+1]; z = go[b*3+2]; }
    else { const float* p = paa + (size_t)b*69 + (t-1)*3; x = p[0]; y = p[1]; z = p[2]; }
    float xe = x + 1e-8f, ye = y + 1e-8f, ze = z + 1e-8f;
    float ang = sqrtf(xe*xe + ye*ye + ze*ze);
    float inv = 1.f / ang;
    float rx = x*inv, ry = y*inv, rz = z*inv;
    float cc = cosf(ang), ss = sinf(ang), mc = 1.f - cc;
    float R[9];
    R[0]=cc+mc*rx*rx;    R[1]=mc*rx*ry-ss*rz; R[2]=mc*rx*rz+ss*ry;
    R[3]=mc*ry*rx+ss*rz; R[4]=cc+mc*ry*ry;    R[5]=mc*ry*rz-ss*rx;
    R[6]=mc*rz*rx-ss*ry; R[7]=mc*rz*ry+ss*rx; R[8]=cc+mc*rz*rz;
#pragma unroll
    for (int q = 0; q < 9; q++) {
      Rl[t][q] = R[q];
      rot_out[(size_t)b*216 + t*9 + q] = R[q];
    }
    if (t > 0) {
#pragma unroll
      for (int q = 0; q < 9; q++) {
        float pv = R[q] - ((q==0||q==4||q==8) ? 1.f : 0.f);
        pfl[(t-1)*9 + q] = pv;
        pf32[(size_t)b*208 + (t-1)*9 + q] = pv;
      }
    }
  }
  if (t < 10) pfl[NP + t] = betas[(size_t)b*10 + t];
  if (t < 72) {
    int j = t / 3;
    const float* x = JRX + t * 11;
    float s = x[0];
#pragma unroll
    for (int l = 0; l < 10; l++) s += betas[(size_t)b*10 + l] * x[1 + l];
    Jl[j][t % 3] = s;
  }
  __syncthreads();
  if (t < 12) {
    int m = t >> 2, n = t & 3;
    Cl[0][t] = (n < 3) ? Rl[0][m*3+n] : Jl[0][m];
  }
  __syncthreads();
  for (int i = 1; i < 24; i++) {
    int p = PAR[i];
    if (t < 12) {
      int m = t >> 2, n = t & 3;
      float v;
      if (n < 3)
        v = Cl[p][m*4+0]*Rl[i][0*3+n] + Cl[p][m*4+1]*Rl[i][1*3+n] + Cl[p][m*4+2]*Rl[i][2*3+n];
      else {
        float r0 = Jl[i][0]-Jl[p][0], r1 = Jl[i][1]-Jl[p][1], r2 = Jl[i][2]-Jl[p][2];
        v = Cl[p][m*4+0]*r0 + Cl[p][m*4+1]*r1 + Cl[p][m*4+2]*r2 + Cl[p][m*4+3];
      }
      Cl[i][t] = v;
    }
    __syncthreads();
  }
  if (t < 72) {
    int j = t / 3, c = t % 3;
    joints_out[(size_t)b*72 + t] = Cl[j][c*4+3] - Cl[0][c*4+3];
  }
  for (int idx = t; idx < 288; idx += 128) {
    int j = idx / 12, r = idx % 12, m = r >> 2, n = r & 3;
    float v;
    if (n < 3) v = Cl[j][m*4+n];
    else v = Cl[j][m*4+3] - (Cl[j][m*4+0]*Jl[j][0] + Cl[j][m*4+1]*Jl[j][1] + Cl[j][m*4+2]*Jl[j][2]);
    A[(size_t)b*288 + idx] = v;
  }
  if (write_pfb && t < 112) {
    unsigned int val = (unsigned int)f2bf(pfl[2*t]) |
                       ((unsigned int)f2bf(pfl[2*t+1]) << 16);
    ((unsigned int*)(pfb + (size_t)b * KP))[t] = val;
  }
}

// K_cvt: pdt local rows [0,CH) = global comps [C0, C0+CH): bf16 [n][k] with
// k<207 -> posedirs[k][n]; 207..216 -> shapedirs l; else 0.
__global__ __launch_bounds__(256) void k_cvt(const float* __restrict__ pd,
    const float* __restrict__ sd, unsigned short* __restrict__ pdt, int C0) {
  __shared__ unsigned short tt[VT][KP + 8];
  int l0 = blockIdx.x * VT;
  int n0 = C0 + l0;
  for (int i = threadIdx.x; i < VT * (KP + 8) / 2; i += 256)
    ((unsigned int*)tt)[i] = 0u;
  __syncthreads();
  for (int idx = threadIdx.x; idx < NP * VT; idx += 256) {
    int k = idx >> 6, n = idx & 63;
    int g = n0 + n;
    float v = (g < NV * 3) ? pd[(size_t)k * (NV * 3) + g] : 0.f;
    tt[n][k] = f2bf(v);
  }
  for (int idx = threadIdx.x; idx < 10 * VT; idx += 256) {
    int n = idx / 10, l = idx % 10;
    int g = n0 + n;
    float v = 0.f;
    if (g < NV * 3) { int vv = g / 3, c = g % 3; v = sd[(size_t)vv * 30 + c * 10 + l]; }
    tt[n][NP + l] = f2bf(v);
  }
  __syncthreads();
  for (int i = threadIdx.x; i < VT * (KP / 2); i += 256) {
    int row = i / (KP / 2), col = i % (KP / 2);
    unsigned int val = ((unsigned int)tt[row][2 * col]) |
                       (((unsigned int)tt[row][2 * col + 1]) << 16);
    ((unsigned int*)pdt)[(size_t)(l0 + row) * (KP / 2) + col] = val;
  }
}

// K2a: fused MFMA pose-GEMM + fp32 LBS. Block: 16 batches x 64 verts, 4 waves.
__global__ __launch_bounds__(256) void k_fused(
    const unsigned short* __restrict__ pfb,   // [B][224] bf16
    const unsigned short* __restrict__ pdt,   // [CH][224] bf16 (local rows)
    const float* __restrict__ A,              // [B][288] f32
    const float* __restrict__ w,              // [NV][24]
    const float* __restrict__ vtm,            // [NV][3]
    float* __restrict__ verts, int C0) {
  int b0 = blockIdx.x * BT;
  int lr0 = blockIdx.y * (VT * 3);        // local pdt row base
  int v0 = C0 / 3 + blockIdx.y * VT;      // global vertex base
  int t = threadIdx.x;
  int lane = t & 63;
  int wv = t >> 6;

  __shared__ unsigned int pfA[16 * 116];
  __shared__ float vp[16 * 196];

  {
    const unsigned int* src = (const unsigned int*)(pfb + (size_t)b0 * KP);
#pragma unroll
    for (int i = 0; i < 7; i++) {
      int d = t + i * 256;
      pfA[(d / 112) * 116 + (d % 112)] = src[d];
    }
  }
  __syncthreads();

  f4v acc0 = {0.f,0.f,0.f,0.f}, acc1 = {0.f,0.f,0.f,0.f}, acc2 = {0.f,0.f,0.f,0.f};
  int q = lane >> 4;
  int m = lane & 15;
  const unsigned short* brow0 = pdt + (size_t)(lr0 + wv*48 + 0  + m) * KP + q * 8;
  const unsigned short* brow1 = pdt + (size_t)(lr0 + wv*48 + 16 + m) * KP + q * 8;
  const unsigned short* brow2 = pdt + (size_t)(lr0 + wv*48 + 32 + m) * KP + q * 8;
  const unsigned int* arow = pfA + m * 116 + q * 4;
#pragma unroll
  for (int ks = 0; ks < 7; ks++) {
    s8v af  = *(const s8v*)(arow + ks * 16);
    s8v bf0 = *(const s8v*)(brow0 + ks * 32);
    s8v bf1 = *(const s8v*)(brow1 + ks * 32);
    s8v bf2 = *(const s8v*)(brow2 + ks * 32);
    acc0 = __builtin_amdgcn_mfma_f32_16x16x32_bf16(af, bf0, acc0, 0, 0, 0);
    acc1 = __builtin_amdgcn_mfma_f32_16x16x32_bf16(af, bf1, acc1, 0, 0, 0);
    acc2 = __builtin_amdgcn_mfma_f32_16x16x32_bf16(af, bf2, acc2, 0, 0, 0);
  }
  // C/D layout (m89-verified): col = lane&15, row = (lane>>4)*4 + reg
#pragma unroll
  for (int r = 0; r < 4; r++) {
    vp[(q*4 + r) * 196 + wv*48 + 0  + m] = acc0[r];
    vp[(q*4 + r) * 196 + wv*48 + 16 + m] = acc1[r];
    vp[(q*4 + r) * 196 + wv*48 + 32 + m] = acc2[r];
  }
  __syncthreads();

  int iv = lane;
  int vglob = v0 + iv;
  bool valid = vglob < NV;
  int vc = valid ? vglob : NV - 1;
  float wr[24];
  {
    const fx4* w4 = (const fx4*)(w + (size_t)vc * 24);
#pragma unroll
    for (int k = 0; k < 6; k++) {
      fx4 t4 = w4[k];
      wr[4*k]=t4.x; wr[4*k+1]=t4.y; wr[4*k+2]=t4.z; wr[4*k+3]=t4.w;
    }
  }
  float vt0 = vtm[(size_t)vc*3+0], vt1 = vtm[(size_t)vc*3+1], vt2 = vtm[(size_t)vc*3+2];

#pragma unroll 1
  for (int u = 0; u < 4; u++) {
    int ib = wv * 4 + u;
    const float* Ab = A + (size_t)(b0 + ib) * 288;
    float T[12];
#pragma unroll
    for (int r = 0; r < 12; r++) T[r] = 0.f;
#pragma unroll
    for (int j = 0; j < 24; j++) {
      float wj = wr[j];
      const float* aj = Ab + j * 12;
      T[0]+=wj*aj[0];  T[1]+=wj*aj[1];  T[2]+=wj*aj[2];  T[3]+=wj*aj[3];
      T[4]+=wj*aj[4];  T[5]+=wj*aj[5];  T[6]+=wj*aj[6];  T[7]+=wj*aj[7];
      T[8]+=wj*aj[8];  T[9]+=wj*aj[9];  T[10]+=wj*aj[10]; T[11]+=wj*aj[11];
    }
    float px = vp[ib*196 + iv*3+0] + vt0;
    float py = vp[ib*196 + iv*3+1] + vt1;
    float pz = vp[ib*196 + iv*3+2] + vt2;
    float o0 = T[0]*px + T[1]*py + T[2]*pz  + T[3];
    float o1 = T[4]*px + T[5]*py + T[6]*pz  + T[7];
    float o2 = T[8]*px + T[9]*py + T[10]*pz + T[11];
    if (valid) {
      float* dst = verts + ((size_t)(b0 + ib) * NV + vglob) * 3;
      dst[0] = o0; dst[1] = o1; dst[2] = o2;
    }
  }
}

// K2b: fp32 fallback (round-3 verified). thread = vertex, block covers 16 batches.
__global__ __launch_bounds__(256) void k_verts(
    const float* __restrict__ betas, const float* __restrict__ vt,
    const float* __restrict__ sd, const float* __restrict__ pd,
    const float* __restrict__ w, const float* __restrict__ pf,
    const float* __restrict__ A, float* __restrict__ verts) {
  int vbase = blockIdx.y * 256;
  int vraw = vbase + threadIdx.x;
  bool valid = vraw < NV;
  int v = valid ? vraw : (NV - 1);
  int b0 = blockIdx.x * BT;

  __shared__ float st[768];

  float sdr[30];
  {
    const fx2* s2 = (const fx2*)(sd + (size_t)v * 30);
#pragma unroll
    for (int q = 0; q < 15; q++) { fx2 tv = s2[q]; sdr[2*q] = tv.x; sdr[2*q+1] = tv.y; }
  }
  float vt0 = vt[(size_t)v*3+0], vt1 = vt[(size_t)v*3+1], vt2 = vt[(size_t)v*3+2];

  float acc[BT][3];
#pragma unroll
  for (int i = 0; i < BT; i++) {
    const float* be = betas + (size_t)(b0 + i) * 10;
    float a0 = vt0, a1 = vt1, a2 = vt2;
#pragma unroll
    for (int l = 0; l < 10; l++) {
      float bl = be[l];
      a0 += bl * sdr[l]; a1 += bl * sdr[10+l]; a2 += bl * sdr[20+l];
    }
    acc[i][0] = a0; acc[i][1] = a1; acc[i][2] = a2;
  }

  const float* pcol = pd + 3 * (size_t)v;
  float cur[12], nxt[12];
#pragma unroll
  for (int r = 0; r < 4; r++) {
    const float* rp = pcol + (size_t)r * 20670;
    cur[3*r] = rp[0]; cur[3*r+1] = rp[1]; cur[3*r+2] = rp[2];
  }
#pragma unroll 1
  for (int k = 0; k < 204; k += 4) {
    if (k < 200) {
#pragma unroll
      for (int r = 0; r < 4; r++) {
        const float* rp = pcol + (size_t)(k + 4 + r) * 20670;
        nxt[3*r] = rp[0]; nxt[3*r+1] = rp[1]; nxt[3*r+2] = rp[2];
      }
    }
#pragma unroll
    for (int i = 0; i < BT; i++) {
      fx4 q = *(const fx4*)(pf + (size_t)(b0 + i) * 208 + k);
      acc[i][0] += q.x*cur[0] + q.y*cur[3] + q.z*cur[6] + q.w*cur[9];
      acc[i][1] += q.x*cur[1] + q.y*cur[4] + q.z*cur[7] + q.w*cur[10];
      acc[i][2] += q.x*cur[2] + q.y*cur[5] + q.z*cur[8] + q.w*cur[11];
    }
#pragma unroll
    for (int r = 0; r < 12; r++) cur[r] = nxt[r];
  }
  {
    float p00,p01,p02,p10,p11,p12,p20,p21,p22;
    { const float* r = pcol + (size_t)204*20670; p00=r[0]; p01=r[1]; p02=r[2]; }
    { const float* r = pcol + (size_t)205*20670; p10=r[0]; p11=r[1]; p12=r[2]; }
    { const float* r = pcol + (size_t)206*20670; p20=r[0]; p21=r[1]; p22=r[2]; }
#pragma unroll
    for (int i = 0; i < BT; i++) {
      const float* pb = pf + (size_t)(b0 + i) * 208;
      float q0 = pb[204], q1 = pb[205], q2 = pb[206];
      acc[i][0] += q0*p00 + q1*p10 + q2*p20;
      acc[i][1] += q0*p01 + q1*p11 + q2*p21;
      acc[i][2] += q0*p02 + q1*p12 + q2*p22;
    }
  }

  float wr[24];
  {
    const fx4* w4 = (const fx4*)(w + (size_t)v * 24);
#pragma unroll
    for (int q = 0; q < 6; q++) {
      fx4 t4 = w4[q];
      wr[4*q]=t4.x; wr[4*q+1]=t4.y; wr[4*q+2]=t4.z; wr[4*q+3]=t4.w;
    }
  }

  int nfl = (NV - vbase) * 3; if (nfl > 768) nfl = 768;
  int nf2 = nfl >> 1;

#pragma unroll 1
  for (int i = 0; i < BT; i++) {
    const float* Ab = A + (size_t)(b0 + i) * 288;
    float T[12];
#pragma unroll
    for (int q = 0; q < 12; q++) T[q] = 0.f;
#pragma unroll
    for (int j = 0; j < 24; j++) {
      float wj = wr[j];
      const fx4* a4 = (const fx4*)(Ab + j * 12);
      fx4 qa = a4[0], qb = a4[1], qc = a4[2];
      T[0]+=wj*qa.x; T[1]+=wj*qa.y; T[2]+=wj*qa.z;  T[3]+=wj*qa.w;
      T[4]+=wj*qb.x; T[5]+=wj*qb.y; T[6]+=wj*qb.z;  T[7]+=wj*qb.w;
      T[8]+=wj*qc.x; T[9]+=wj*qc.y; T[10]+=wj*qc.z; T[11]+=wj*qc.w;
    }
    float x = acc[i][0], y = acc[i][1], z = acc[i][2];
    float o0 = T[0]*x + T[1]*y + T[2]*z  + T[3];
    float o1 = T[4]*x + T[5]*y + T[6]*z  + T[7];
    float o2 = T[8]*x + T[9]*y + T[10]*z + T[11];
    __syncthreads();
    st[threadIdx.x*3+0] = o0; st[threadIdx.x*3+1] = o1; st[threadIdx.x*3+2] = o2;
    __syncthreads();
    float* dst = verts + (size_t)(b0 + i) * (NV*3) + (size_t)vbase * 3;
    const fx2* s2 = (const fx2*)st;
    int q = threadIdx.x;
    if (q < nf2) __builtin_nontemporal_store(s2[q], (fx2*)dst + q);
    q += 256;
    if (q < nf2) __builtin_nontemporal_store(s2[q], (fx2*)dst + q);
  }
}

// K3: j17 from unshifted verts; write shifted j17; shift verts in place.
__global__ __launch_bounds__(256) void k_j17s(const float* __restrict__ jrh,
    float* __restrict__ verts, float* __restrict__ j17_out) {
  int b = blockIdx.x;
  float acc[17][3];
#pragma unroll
  for (int j = 0; j < 17; j++) { acc[j][0]=0.f; acc[j][1]=0.f; acc[j][2]=0.f; }
  float* vb = verts + (size_t)b * NV * 3;
  for (int v = threadIdx.x; v < NV; v += 256) {
    float x = vb[v*3], y = vb[v*3+1], z = vb[v*3+2];
#pragma unroll
    for (int j = 0; j < 17; j++) {
      float r = jrh[(size_t)j * NV + v];
      acc[j][0] += r*x; acc[j][1] += r*y; acc[j][2] += r*z;
    }
  }
#pragma unroll
  for (int j = 0; j < 17; j++) {
#pragma unroll
    for (int c = 0; c < 3; c++) {
      for (int off = 32; off; off >>= 1) acc[j][c] += __shfl_xor(acc[j][c], off, 64);
    }
  }
  __shared__ float red[4][51];
  __shared__ float fin[51];
  int wave = threadIdx.x >> 6, lane = threadIdx.x & 63;
  if (lane == 0) {
#pragma unroll
    for (int j = 0; j < 17; j++) {
      red[wave][j*3+0] = acc[j][0]; red[wave][j*3+1] = acc[j][1]; red[wave][j*3+2] = acc[j][2];
    }
  }
  __syncthreads();
  if (threadIdx.x < 51)
    fin[threadIdx.x] = red[0][threadIdx.x] + red[1][threadIdx.x] + red[2][threadIdx.x] + red[3][threadIdx.x];
  __syncthreads();
  if (threadIdx.x < 51) {
    int c = threadIdx.x % 3;
    j17_out[(size_t)b*51 + threadIdx.x] = fin[threadIdx.x] - fin[c];
  }
  float r0 = fin[0], r1 = fin[1], r2 = fin[2];
  for (int idx = threadIdx.x; idx < NV * 3; idx += 256) {
    int c = idx % 3;
    float rr = (c == 0) ? r0 : (c == 1 ? r1 : r2);
    vb[idx] -= rr;
  }
}

extern "C" void kernel_launch(void* const* d_in, const int* in_sizes, int n_in,
                              void* d_out, int out_size, void* d_ws, size_t ws_size,
                              hipStream_t stream) {
  const float* pose  = (const float*)d_in[0];
  const float* betas = (const float*)d_in[1];
  const float* glob  = (const float*)d_in[2];
  const float* vtm   = (const float*)d_in[3];
  const float* sd    = (const float*)d_in[4];
  const float* pd    = (const float*)d_in[5];
  const float* JR    = (const float*)d_in[6];
  const float* JRh   = (const float*)d_in[7];
  const float* w     = (const float*)d_in[8];
  float* out = (float*)d_out;
  char* wsb = (char*)d_ws;
  float* A             = (float*)(wsb + WSB_A);
  float* JRX           = (float*)(wsb + WSB_JRX);
  float* pf32          = (float*)(wsb + WSB_PF32);
  unsigned short* pfb  = (unsigned short*)(wsb + WSB_PFB);
  unsigned short* pdt  = (unsigned short*)(wsb + WSB_PDT);

  // ws tiers: pdt chunk must fit. base = 2,494,464 B; row = 448 B.
  int nch;
  if      (ws_size >= (size_t)2494464 + (size_t)NR * 448)        nch = 1;  // 11,784,192
  else if (ws_size >= (size_t)2494464 + (size_t)(NR/2) * 448)    nch = 2;  //  7,139,328
  else if (ws_size >= (size_t)2494464 + (size_t)(NR/6) * 448)    nch = 6;  //  4,042,752
  else                                                           nch = 0;  // fp32 fallback

  k_jrx<<<72, 256, 0, stream>>>(JR, vtm, sd, JRX);
  k_pose<<<B, 128, 0, stream>>>(glob, pose, betas, JRX, out + OFF_R, out + OFF_J,
                                pf32, pfb, A, nch ? 1 : 0);
  if (nch) {
    int CH = NR / nch;                       // comps per chunk (mult of 192)
    for (int c = 0; c < nch; c++) {
      k_cvt<<<CH / VT, 256, 0, stream>>>(pd, sd, pdt, c * CH);
      k_fused<<<dim3(B / BT, CH / (VT * 3)), 256, 0, stream>>>(pfb, pdt, A, w, vtm,
                                                               out, c * CH);
    }
  } else {
    k_verts<<<dim3(B / BT, 27), 256, 0, stream>>>(betas, vtm, sd, pd, w, pf32, A, out);
  }
  k_j17s<<<B, 256, 0, stream>>>(JRh, out, out + OFF_J17);
}

// Round 8
// 413.129 us; speedup vs baseline: 1.3150x; 1.3150x over previous
//
#include <hip/hip_runtime.h>
#include <math.h>

#define B 1024
#define NV 6890
#define NP 207
#define KP 224      // padded K (207 pf + 10 betas + 7 zero)
#define NR 20736    // padded comp rows (27*768)
#define VTB 256     // verts per block tile
#define BT 16       // batches per tile

typedef float fx2 __attribute__((ext_vector_type(2)));
typedef float fx4 __attribute__((ext_vector_type(4)));
typedef short s8v __attribute__((ext_vector_type(8)));   // 8 bf16 (MFMA A/B frag)
typedef float f4v __attribute__((ext_vector_type(4)));   // MFMA C/D frag

// ---- output layout (floats) ----
#define OFF_J   21166080
#define OFF_J17 21239808
#define OFF_R   21292032

// ---- workspace layout (byte offsets) ----
#define WSB_A    0           // [1024][288] f32   1,179,648
#define WSB_JRX  1179648     // [72][11] f32      3,168
#define WSB_PF32 1183744     // [1024][208] f32   851,968  (ends 2,035,712)
#define WSB_PFB  2035712     // [1024][224] bf16  458,752  (big path only)
#define WSB_PDT  2494464     // [CH][224] bf16    chunk-sized (big path only)

__device__ __constant__ int PAR[24] = {0,0,0,0,1,2,3,4,5,6,7,8,9,9,9,12,13,14,16,17,18,19,20,21};

__device__ inline unsigned short f2bf(float f) {
  unsigned int u = __builtin_bit_cast(unsigned int, f);
  unsigned int r = (u + 0x7FFFu + ((u >> 16) & 1u)) >> 16;
  return (unsigned short)r;
}

// K0: JRX[(j*3+c)*11 + l] = sum_v JR[j,v] * (l==0 ? v_template[v,c] : shapedirs[v,c,l-1])
__global__ __launch_bounds__(256) void k_jrx(const float* __restrict__ JR,
    const float* __restrict__ vtm, const float* __restrict__ sd,
    float* __restrict__ JRX) {
  int o = blockIdx.x;
  int j = o / 3, c = o % 3;
  float acc[11];
#pragma unroll
  for (int q = 0; q < 11; q++) acc[q] = 0.f;
  for (int v = threadIdx.x; v < NV; v += 256) {
    float r = JR[(size_t)j * NV + v];
    acc[0] += r * vtm[(size_t)v * 3 + c];
    const float* s = sd + (size_t)v * 30 + c * 10;
#pragma unroll
    for (int l = 0; l < 10; l++) acc[1 + l] += r * s[l];
  }
#pragma unroll
  for (int q = 0; q < 11; q++) {
    for (int off = 32; off; off >>= 1) acc[q] += __shfl_xor(acc[q], off, 64);
  }
  __shared__ float red[4][11];
  int wave = threadIdx.x >> 6, lane = threadIdx.x & 63;
  if (lane == 0) {
#pragma unroll
    for (int q = 0; q < 11; q++) red[wave][q] = acc[q];
  }
  __syncthreads();
  if (threadIdx.x < 11) {
    int q = threadIdx.x;
    JRX[o * 11 + q] = red[0][q] + red[1][q] + red[2][q] + red[3][q];
  }
}

// K1: rodrigues, pf (f32 + optional bf16), joints, chain, A
__global__ __launch_bounds__(128) void k_pose(const float* __restrict__ go,
    const float* __restrict__ paa, const float* __restrict__ betas,
    const float* __restrict__ JRX, float* __restrict__ rot_out,
    float* __restrict__ joints_out, float* __restrict__ pf32,
    unsigned short* __restrict__ pfb, float* __restrict__ A, int write_pfb) {
  int b = blockIdx.x, t = threadIdx.x;
  __shared__ float Rl[24][9];
  __shared__ float Jl[24][3];
  __shared__ float Cl[24][12];
  __shared__ float pfl[KP];

  for (int i = t; i < KP; i += 128) pfl[i] = 0.f;
  __syncthreads();

  if (t < 24) {
    float x, y, z;
    if (t == 0) { x = go[b*3]; y = go[b*3+1]; z = go[b*3+2]; }
    else { const float* p = paa + (size_t)b*69 + (t-1)*3; x = p[0]; y = p[1]; z = p[2]; }
    float xe = x + 1e-8f, ye = y + 1e-8f, ze = z + 1e-8f;
    float ang = sqrtf(xe*xe + ye*ye + ze*ze);
    float inv = 1.f / ang;
    float rx = x*inv, ry = y*inv, rz = z*inv;
    float cc = cosf(ang), ss = sinf(ang), mc = 1.f - cc;
    float R[9];
    R[0]=cc+mc*rx*rx;    R[1]=mc*rx*ry-ss*rz; R[2]=mc*rx*rz+ss*ry;
    R[3]=mc*ry*rx+ss*rz; R[4]=cc+mc*ry*ry;    R[5]=mc*ry*rz-ss*rx;
    R[6]=mc*rz*rx-ss*ry; R[7]=mc*rz*ry+ss*rx; R[8]=cc+mc*rz*rz;
#pragma unroll
    for (int q = 0; q < 9; q++) {
      Rl[t][q] = R[q];
      rot_out[(size_t)b*216 + t*9 + q] = R[q];
    }
    if (t > 0) {
#pragma unroll
      for (int q = 0; q < 9; q++) {
        float pv = R[q] - ((q==0||q==4||q==8) ? 1.f : 0.f);
        pfl[(t-1)*9 + q] = pv;
        pf32[(size_t)b*208 + (t-1)*9 + q] = pv;
      }
    }
  }
  if (t < 10) pfl[NP + t] = betas[(size_t)b*10 + t];
  if (t < 72) {
    int j = t / 3;
    const float* x = JRX + t * 11;
    float s = x[0];
#pragma unroll
    for (int l = 0; l < 10; l++) s += betas[(size_t)b*10 + l] * x[1 + l];
    Jl[j][t % 3] = s;
  }
  __syncthreads();
  if (t < 12) {
    int m = t >> 2, n = t & 3;
    Cl[0][t] = (n < 3) ? Rl[0][m*3+n] : Jl[0][m];
  }
  __syncthreads();
  for (int i = 1; i < 24; i++) {
    int p = PAR[i];
    if (t < 12) {
      int m = t >> 2, n = t & 3;
      float v;
      if (n < 3)
        v = Cl[p][m*4+0]*Rl[i][0*3+n] + Cl[p][m*4+1]*Rl[i][1*3+n] + Cl[p][m*4+2]*Rl[i][2*3+n];
      else {
        float r0 = Jl[i][0]-Jl[p][0], r1 = Jl[i][1]-Jl[p][1], r2 = Jl[i][2]-Jl[p][2];
        v = Cl[p][m*4+0]*r0 + Cl[p][m*4+1]*r1 + Cl[p][m*4+2]*r2 + Cl[p][m*4+3];
      }
      Cl[i][t] = v;
    }
    __syncthreads();
  }
  if (t < 72) {
    int j = t / 3, c = t % 3;
    joints_out[(size_t)b*72 + t] = Cl[j][c*4+3] - Cl[0][c*4+3];
  }
  for (int idx = t; idx < 288; idx += 128) {
    int j = idx / 12, r = idx % 12, m = r >> 2, n = r & 3;
    float v;
    if (n < 3) v = Cl[j][m*4+n];
    else v = Cl[j][m*4+3] - (Cl[j][m*4+0]*Jl[j][0] + Cl[j][m*4+1]*Jl[j][1] + Cl[j][m*4+2]*Jl[j][2]);
    A[(size_t)b*288 + idx] = v;
  }
  if (write_pfb && t < 112) {
    unsigned int val = (unsigned int)f2bf(pfl[2*t]) |
                       ((unsigned int)f2bf(pfl[2*t+1]) << 16);
    ((unsigned int*)(pfb + (size_t)b * KP))[t] = val;
  }
}

// K_cvt: pdt local rows [0,CH) = global comps [C0, C0+CH): bf16 [n][k] with
// k<207 -> posedirs[k][n]; 207..216 -> shapedirs l; else 0.
#define VTC 64
__global__ __launch_bounds__(256) void k_cvt(const float* __restrict__ pd,
    const float* __restrict__ sd, unsigned short* __restrict__ pdt, int C0) {
  __shared__ unsigned short tt[VTC][KP + 8];
  int l0 = blockIdx.x * VTC;
  int n0 = C0 + l0;
  for (int i = threadIdx.x; i < VTC * (KP + 8) / 2; i += 256)
    ((unsigned int*)tt)[i] = 0u;
  __syncthreads();
  for (int idx = threadIdx.x; idx < NP * VTC; idx += 256) {
    int k = idx >> 6, n = idx & 63;
    int g = n0 + n;
    float v = (g < NV * 3) ? pd[(size_t)k * (NV * 3) + g] : 0.f;
    tt[n][k] = f2bf(v);
  }
  for (int idx = threadIdx.x; idx < 10 * VTC; idx += 256) {
    int n = idx / 10, l = idx % 10;
    int g = n0 + n;
    float v = 0.f;
    if (g < NV * 3) { int vv = g / 3, c = g % 3; v = sd[(size_t)vv * 30 + c * 10 + l]; }
    tt[n][NP + l] = f2bf(v);
  }
  __syncthreads();
  for (int i = threadIdx.x; i < VTC * (KP / 2); i += 256) {
    int row = i / (KP / 2), col = i % (KP / 2);
    unsigned int val = ((unsigned int)tt[row][2 * col]) |
                       (((unsigned int)tt[row][2 * col + 1]) << 16);
    ((unsigned int*)pdt)[(size_t)(l0 + row) * (KP / 2) + col] = val;
  }
}

// K2a: fused MFMA pose-GEMM + fp32 LBS. Block: 16 batches x 256 verts, 4 waves.
// Phase 1: MFMA 768 comps x 16 batches -> vp LDS. Phase 2: round-3 k_verts
// epilogue (thread=vertex, per-lane float4 A loads) reading vp.
// grid (x = B/16, y = rows/768): x fastest -> pdt-slice sharing across XCD L2.
#define VPLD 772    // vp row pad (2-way bank conflict = free)
__global__ __launch_bounds__(256) void k_fused(
    const unsigned short* __restrict__ pfb,   // [B][224] bf16
    const unsigned short* __restrict__ pdt,   // [CH][224] bf16 (local rows)
    const float* __restrict__ A,              // [B][288] f32
    const float* __restrict__ w,              // [NV][24]
    const float* __restrict__ vtm,            // [NV][3]
    float* __restrict__ verts, int C0) {
  int b0 = blockIdx.x * BT;
  int lr0 = blockIdx.y * (VTB * 3);       // local pdt row base
  int v0 = C0 / 3 + blockIdx.y * VTB;     // global vertex base
  int t = threadIdx.x;
  int lane = t & 63;
  int wv = t >> 6;

  __shared__ unsigned int pfA[16 * 116];  // 7,424 B
  __shared__ float vp[16 * VPLD];         // 49,408 B  [batch][768 comps]

  { // stage pf rows b0..b0+15 (contiguous 1792 dwords) into padded LDS
    const unsigned int* src = (const unsigned int*)(pfb + (size_t)b0 * KP);
#pragma unroll
    for (int i = 0; i < 7; i++) {
      int d = t + i * 256;
      pfA[(d / 112) * 116 + (d % 112)] = src[d];
    }
  }
  __syncthreads();

  // ---- phase 1: MFMA. wave wv covers comps [wv*192, wv*192+192) ----
  int q = lane >> 4;       // k-chunk selector
  int m = lane & 15;       // A row (batch) / B row (comp)
  s8v af[7];
  {
    const unsigned int* arow = pfA + m * 116 + q * 4;
#pragma unroll
    for (int ks = 0; ks < 7; ks++) af[ks] = *(const s8v*)(arow + ks * 16);
  }
  const unsigned short* browb = pdt + (size_t)(lr0 + wv * 192 + m) * KP + q * 8;
#pragma unroll 1
  for (int f = 0; f < 12; f++) {
    const unsigned short* br = browb + (size_t)f * 16 * KP;
    f4v acc = {0.f, 0.f, 0.f, 0.f};
#pragma unroll
    for (int ks = 0; ks < 7; ks++)
      acc = __builtin_amdgcn_mfma_f32_16x16x32_bf16(af[ks], *(const s8v*)(br + ks * 32), acc, 0, 0, 0);
    // C/D layout (HW-validated round 7): comp col = m, batch row = q*4 + r
    int cbase = wv * 192 + f * 16 + m;
#pragma unroll
    for (int r = 0; r < 4; r++) vp[(q * 4 + r) * VPLD + cbase] = acc[r];
  }
  __syncthreads();

  // ---- phase 2: LBS epilogue (round-3 proven structure) ----
  int vglob = v0 + t;
  bool valid = vglob < NV;
  int vc = valid ? vglob : NV - 1;
  float wr[24];
  {
    const fx4* w4 = (const fx4*)(w + (size_t)vc * 24);
#pragma unroll
    for (int k = 0; k < 6; k++) {
      fx4 t4 = w4[k];
      wr[4*k]=t4.x; wr[4*k+1]=t4.y; wr[4*k+2]=t4.z; wr[4*k+3]=t4.w;
    }
  }
  float vt0 = vtm[(size_t)vc*3+0], vt1 = vtm[(size_t)vc*3+1], vt2 = vtm[(size_t)vc*3+2];

#pragma unroll 1
  for (int ib = 0; ib < BT; ib++) {
    const float* Ab = A + (size_t)(b0 + ib) * 288;
    float T[12];
#pragma unroll
    for (int r = 0; r < 12; r++) T[r] = 0.f;
#pragma unroll
    for (int j = 0; j < 24; j++) {
      float wj = wr[j];
      const fx4* a4 = (const fx4*)(Ab + j * 12);
      fx4 qa = a4[0], qb = a4[1], qc = a4[2];
      T[0]+=wj*qa.x; T[1]+=wj*qa.y; T[2]+=wj*qa.z;  T[3]+=wj*qa.w;
      T[4]+=wj*qb.x; T[5]+=wj*qb.y; T[6]+=wj*qb.z;  T[7]+=wj*qb.w;
      T[8]+=wj*qc.x; T[9]+=wj*qc.y; T[10]+=wj*qc.z; T[11]+=wj*qc.w;
    }
    float px = vp[ib * VPLD + t*3+0] + vt0;
    float py = vp[ib * VPLD + t*3+1] + vt1;
    float pz = vp[ib * VPLD + t*3+2] + vt2;
    float o0 = T[0]*px + T[1]*py + T[2]*pz  + T[3];
    float o1 = T[4]*px + T[5]*py + T[6]*pz  + T[7];
    float o2 = T[8]*px + T[9]*py + T[10]*pz + T[11];
    if (valid) {
      float* dst = verts + ((size_t)(b0 + ib) * NV + vglob) * 3;
      dst[0] = o0; dst[1] = o1; dst[2] = o2;
    }
  }
}

// K2b: fp32 fallback (round-3 verified). thread = vertex, block covers 16 batches.
__global__ __launch_bounds__(256) void k_verts(
    const float* __restrict__ betas, const float* __restrict__ vt,
    const float* __restrict__ sd, const float* __restrict__ pd,
    const float* __restrict__ w, const float* __restrict__ pf,
    const float* __restrict__ A, float* __restrict__ verts) {
  int vbase = blockIdx.y * 256;
  int vraw = vbase + threadIdx.x;
  bool valid = vraw < NV;
  int v = valid ? vraw : (NV - 1);
  int b0 = blockIdx.x * BT;

  float sdr[30];
  {
    const fx2* s2 = (const fx2*)(sd + (size_t)v * 30);
#pragma unroll
    for (int q = 0; q < 15; q++) { fx2 tv = s2[q]; sdr[2*q] = tv.x; sdr[2*q+1] = tv.y; }
  }
  float vt0 = vt[(size_t)v*3+0], vt1 = vt[(size_t)v*3+1], vt2 = vt[(size_t)v*3+2];

  float acc[BT][3];
#pragma unroll
  for (int i = 0; i < BT; i++) {
    const float* be = betas + (size_t)(b0 + i) * 10;
    float a0 = vt0, a1 = vt1, a2 = vt2;
#pragma unroll
    for (int l = 0; l < 10; l++) {
      float bl = be[l];
      a0 += bl * sdr[l]; a1 += bl * sdr[10+l]; a2 += bl * sdr[20+l];
    }
    acc[i][0] = a0; acc[i][1] = a1; acc[i][2] = a2;
  }

  const float* pcol = pd + 3 * (size_t)v;
  float cur[12], nxt[12];
#pragma unroll
  for (int r = 0; r < 4; r++) {
    const float* rp = pcol + (size_t)r * 20670;
    cur[3*r] = rp[0]; cur[3*r+1] = rp[1]; cur[3*r+2] = rp[2];
  }
#pragma unroll 1
  for (int k = 0; k < 204; k += 4) {
    if (k < 200) {
#pragma unroll
      for (int r = 0; r < 4; r++) {
        const float* rp = pcol + (size_t)(k + 4 + r) * 20670;
        nxt[3*r] = rp[0]; nxt[3*r+1] = rp[1]; nxt[3*r+2] = rp[2];
      }
    }
#pragma unroll
    for (int i = 0; i < BT; i++) {
      fx4 q = *(const fx4*)(pf + (size_t)(b0 + i) * 208 + k);
      acc[i][0] += q.x*cur[0] + q.y*cur[3] + q.z*cur[6] + q.w*cur[9];
      acc[i][1] += q.x*cur[1] + q.y*cur[4] + q.z*cur[7] + q.w*cur[10];
      acc[i][2] += q.x*cur[2] + q.y*cur[5] + q.z*cur[8] + q.w*cur[11];
    }
#pragma unroll
    for (int r = 0; r < 12; r++) cur[r] = nxt[r];
  }
  {
    float p00,p01,p02,p10,p11,p12,p20,p21,p22;
    { const float* r = pcol + (size_t)204*20670; p00=r[0]; p01=r[1]; p02=r[2]; }
    { const float* r = pcol + (size_t)205*20670; p10=r[0]; p11=r[1]; p12=r[2]; }
    { const float* r = pcol + (size_t)206*20670; p20=r[0]; p21=r[1]; p22=r[2]; }
#pragma unroll
    for (int i = 0; i < BT; i++) {
      const float* pb = pf + (size_t)(b0 + i) * 208;
      float q0 = pb[204], q1 = pb[205], q2 = pb[206];
      acc[i][0] += q0*p00 + q1*p10 + q2*p20;
      acc[i][1] += q0*p01 + q1*p11 + q2*p21;
      acc[i][2] += q0*p02 + q1*p12 + q2*p22;
    }
  }

  float wr[24];
  {
    const fx4* w4 = (const fx4*)(w + (size_t)v * 24);
#pragma unroll
    for (int q = 0; q < 6; q++) {
      fx4 t4 = w4[q];
      wr[4*q]=t4.x; wr[4*q+1]=t4.y; wr[4*q+2]=t4.z; wr[4*q+3]=t4.w;
    }
  }

#pragma unroll 1
  for (int i = 0; i < BT; i++) {
    const float* Ab = A + (size_t)(b0 + i) * 288;
    float T[12];
#pragma unroll
    for (int q = 0; q < 12; q++) T[q] = 0.f;
#pragma unroll
    for (int j = 0; j < 24; j++) {
      float wj = wr[j];
      const fx4* a4 = (const fx4*)(Ab + j * 12);
      fx4 qa = a4[0], qb = a4[1], qc = a4[2];
      T[0]+=wj*qa.x; T[1]+=wj*qa.y; T[2]+=wj*qa.z;  T[3]+=wj*qa.w;
      T[4]+=wj*qb.x; T[5]+=wj*qb.y; T[6]+=wj*qb.z;  T[7]+=wj*qb.w;
      T[8]+=wj*qc.x; T[9]+=wj*qc.y; T[10]+=wj*qc.z; T[11]+=wj*qc.w;
    }
    float x = acc[i][0], y = acc[i][1], z = acc[i][2];
    float o0 = T[0]*x + T[1]*y + T[2]*z  + T[3];
    float o1 = T[4]*x + T[5]*y + T[6]*z  + T[7];
    float o2 = T[8]*x + T[9]*y + T[10]*z + T[11];
    if (valid) {
      float* dst = verts + ((size_t)(b0 + i) * NV + vraw) * 3;
      dst[0] = o0; dst[1] = o1; dst[2] = o2;
    }
  }
}

// K3: j17 from unshifted verts; write shifted j17; shift verts in place.
__global__ __launch_bounds__(256) void k_j17s(const float* __restrict__ jrh,
    float* __restrict__ verts, float* __restrict__ j17_out) {
  int b = blockIdx.x;
  float acc[17][3];
#pragma unroll
  for (int j = 0; j < 17; j++) { acc[j][0]=0.f; acc[j][1]=0.f; acc[j][2]=0.f; }
  float* vb = verts + (size_t)b * NV * 3;
  for (int v = threadIdx.x; v < NV; v += 256) {
    float x = vb[v*3], y = vb[v*3+1], z = vb[v*3+2];
#pragma unroll
    for (int j = 0; j < 17; j++) {
      float r = jrh[(size_t)j * NV + v];
      acc[j][0] += r*x; acc[j][1] += r*y; acc[j][2] += r*z;
    }
  }
#pragma unroll
  for (int j = 0; j < 17; j++) {
#pragma unroll
    for (int c = 0; c < 3; c++) {
      for (int off = 32; off; off >>= 1) acc[j][c] += __shfl_xor(acc[j][c], off, 64);
    }
  }
  __shared__ float red[4][51];
  __shared__ float fin[51];
  int wave = threadIdx.x >> 6, lane = threadIdx.x & 63;
  if (lane == 0) {
#pragma unroll
    for (int j = 0; j < 17; j++) {
      red[wave][j*3+0] = acc[j][0]; red[wave][j*3+1] = acc[j][1]; red[wave][j*3+2] = acc[j][2];
    }
  }
  __syncthreads();
  if (threadIdx.x < 51)
    fin[threadIdx.x] = red[0][threadIdx.x] + red[1][threadIdx.x] + red[2][threadIdx.x] + red[3][threadIdx.x];
  __syncthreads();
  if (threadIdx.x < 51) {
    int c = threadIdx.x % 3;
    j17_out[(size_t)b*51 + threadIdx.x] = fin[threadIdx.x] - fin[c];
  }
  float r0 = fin[0], r1 = fin[1], r2 = fin[2];
  for (int idx = threadIdx.x; idx < NV * 3; idx += 256) {
    int c = idx % 3;
    float rr = (c == 0) ? r0 : (c == 1 ? r1 : r2);
    vb[idx] -= rr;
  }
}

extern "C" void kernel_launch(void* const* d_in, const int* in_sizes, int n_in,
                              void* d_out, int out_size, void* d_ws, size_t ws_size,
                              hipStream_t stream) {
  const float* pose  = (const float*)d_in[0];
  const float* betas = (const float*)d_in[1];
  const float* glob  = (const float*)d_in[2];
  const float* vtm   = (const float*)d_in[3];
  const float* sd    = (const float*)d_in[4];
  const float* pd    = (const float*)d_in[5];
  const float* JR    = (const float*)d_in[6];
  const float* JRh   = (const float*)d_in[7];
  const float* w     = (const float*)d_in[8];
  float* out = (float*)d_out;
  char* wsb = (char*)d_ws;
  float* A             = (float*)(wsb + WSB_A);
  float* JRX           = (float*)(wsb + WSB_JRX);
  float* pf32          = (float*)(wsb + WSB_PF32);
  unsigned short* pfb  = (unsigned short*)(wsb + WSB_PFB);
  unsigned short* pdt  = (unsigned short*)(wsb + WSB_PDT);

  // ws tiers (chunks multiple of 768 rows). nch=1 proven available (round 7).
  int nch;
  if      (ws_size >= (size_t)2494464 + (size_t)NR * 448)        nch = 1;  // 11,784,192
  else if (ws_size >= (size_t)2494464 + (size_t)(NR/3) * 448)    nch = 3;  //  5,591,040
  else                                                           nch = 0;  // fp32 fallback

  k_jrx<<<72, 256, 0, stream>>>(JR, vtm, sd, JRX);
  k_pose<<<B, 128, 0, stream>>>(glob, pose, betas, JRX, out + OFF_R, out + OFF_J,
                                pf32, pfb, A, nch ? 1 : 0);
  if (nch) {
    int CH = NR / nch;                       // rows per chunk (mult of 768)
    for (int c = 0; c < nch; c++) {
      k_cvt<<<CH / VTC, 256, 0, stream>>>(pd, sd, pdt, c * CH);
      k_fused<<<dim3(B / BT, CH / (VTB * 3)), 256, 0, stream>>>(pfb, pdt, A, w, vtm,
                                                                out, c * CH);
    }
  } else {
    k_verts<<<dim3(B / BT, 27), 256, 0, stream>>>(betas, vtm, sd, pd, w, pf32, A, out);
  }
  k_j17s<<<B, 256, 0, stream>>>(JRh, out, out + OFF_J17);
}

// Round 10
// 346.847 us; speedup vs baseline: 1.5663x; 1.1911x over previous
//
#include <hip/hip_runtime.h>
#include <math.h>

#define B 1024
#define NV 6890
#define NP 207
#define KP 224      // padded K (207 pf + 10 betas + 7 zero)
#define NR 20736    // padded comp rows (27*768)
#define VTB 256     // verts per block tile
#define BT 16       // batches per tile
#define VPS 20      // vp_bf row stride in u16 (40 B: b64-aligned writes)

typedef float fx2 __attribute__((ext_vector_type(2)));
typedef float fx4 __attribute__((ext_vector_type(4)));
typedef short s8v __attribute__((ext_vector_type(8)));   // 8 bf16 (MFMA A/B frag)
typedef float f4v __attribute__((ext_vector_type(4)));   // MFMA C/D frag

// ---- output layout (floats) ----
#define OFF_J   21166080
#define OFF_J17 21239808
#define OFF_R   21292032

// ---- workspace layout (byte offsets) ----
#define WSB_A    0           // [1024][288] f32   1,179,648
#define WSB_JRX  1179648     // [72][11] f32      3,168
#define WSB_PF32 1183744     // [1024][208] f32   851,968  (ends 2,035,712)
#define WSB_PFB  2035712     // [1024][224] bf16  458,752  (big path only)
#define WSB_PDT  2494464     // [CH][224] bf16    chunk-sized (big path only)

__device__ __constant__ int PAR[24] = {0,0,0,0,1,2,3,4,5,6,7,8,9,9,9,12,13,14,16,17,18,19,20,21};

__device__ inline unsigned short f2bf(float f) {
  unsigned int u = __builtin_bit_cast(unsigned int, f);
  unsigned int r = (u + 0x7FFFu + ((u >> 16) & 1u)) >> 16;
  return (unsigned short)r;
}

// K0: JRX[(j*3+c)*11 + l] = sum_v JR[j,v] * (l==0 ? v_template[v,c] : shapedirs[v,c,l-1])
__global__ __launch_bounds__(256) void k_jrx(const float* __restrict__ JR,
    const float* __restrict__ vtm, const float* __restrict__ sd,
    float* __restrict__ JRX) {
  int o = blockIdx.x;
  int j = o / 3, c = o % 3;
  float acc[11];
#pragma unroll
  for (int q = 0; q < 11; q++) acc[q] = 0.f;
  for (int v = threadIdx.x; v < NV; v += 256) {
    float r = JR[(size_t)j * NV + v];
    acc[0] += r * vtm[(size_t)v * 3 + c];
    const float* s = sd + (size_t)v * 30 + c * 10;
#pragma unroll
    for (int l = 0; l < 10; l++) acc[1 + l] += r * s[l];
  }
#pragma unroll
  for (int q = 0; q < 11; q++) {
    for (int off = 32; off; off >>= 1) acc[q] += __shfl_xor(acc[q], off, 64);
  }
  __shared__ float red[4][11];
  int wave = threadIdx.x >> 6, lane = threadIdx.x & 63;
  if (lane == 0) {
#pragma unroll
    for (int q = 0; q < 11; q++) red[wave][q] = acc[q];
  }
  __syncthreads();
  if (threadIdx.x < 11) {
    int q = threadIdx.x;
    JRX[o * 11 + q] = red[0][q] + red[1][q] + red[2][q] + red[3][q];
  }
}

// K1: rodrigues, pf (f32 + optional bf16), joints, chain, A
__global__ __launch_bounds__(128) void k_pose(const float* __restrict__ go,
    const float* __restrict__ paa, const float* __restrict__ betas,
    const float* __restrict__ JRX, float* __restrict__ rot_out,
    float* __restrict__ joints_out, float* __restrict__ pf32,
    unsigned short* __restrict__ pfb, float* __restrict__ A, int write_pfb) {
  int b = blockIdx.x, t = threadIdx.x;
  __shared__ float Rl[24][9];
  __shared__ float Jl[24][3];
  __shared__ float Cl[24][12];
  __shared__ float pfl[KP];

  for (int i = t; i < KP; i += 128) pfl[i] = 0.f;
  __syncthreads();

  if (t < 24) {
    float x, y, z;
    if (t == 0) { x = go[b*3]; y = go[b*3+1]; z = go[b*3+2]; }
    else { const float* p = paa + (size_t)b*69 + (t-1)*3; x = p[0]; y = p[1]; z = p[2]; }
    float xe = x + 1e-8f, ye = y + 1e-8f, ze = z + 1e-8f;
    float ang = sqrtf(xe*xe + ye*ye + ze*ze);
    float inv = 1.f / ang;
    float rx = x*inv, ry = y*inv, rz = z*inv;
    float cc = cosf(ang), ss = sinf(ang), mc = 1.f - cc;
    float R[9];
    R[0]=cc+mc*rx*rx;    R[1]=mc*rx*ry-ss*rz; R[2]=mc*rx*rz+ss*ry;
    R[3]=mc*ry*rx+ss*rz; R[4]=cc+mc*ry*ry;    R[5]=mc*ry*rz-ss*rx;
    R[6]=mc*rz*rx-ss*ry; R[7]=mc*rz*ry+ss*rx; R[8]=cc+mc*rz*rz;
#pragma unroll
    for (int q = 0; q < 9; q++) {
      Rl[t][q] = R[q];
      rot_out[(size_t)b*216 + t*9 + q] = R[q];
    }
    if (t > 0) {
#pragma unroll
      for (int q = 0; q < 9; q++) {
        float pv = R[q] - ((q==0||q==4||q==8) ? 1.f : 0.f);
        pfl[(t-1)*9 + q] = pv;
        pf32[(size_t)b*208 + (t-1)*9 + q] = pv;
      }
    }
  }
  if (t < 10) pfl[NP + t] = betas[(size_t)b*10 + t];
  if (t < 72) {
    int j = t / 3;
    const float* x = JRX + t * 11;
    float s = x[0];
#pragma unroll
    for (int l = 0; l < 10; l++) s += betas[(size_t)b*10 + l] * x[1 + l];
    Jl[j][t % 3] = s;
  }
  __syncthreads();
  if (t < 12) {
    int m = t >> 2, n = t & 3;
    Cl[0][t] = (n < 3) ? Rl[0][m*3+n] : Jl[0][m];
  }
  __syncthreads();
  for (int i = 1; i < 24; i++) {
    int p = PAR[i];
    if (t < 12) {
      int m = t >> 2, n = t & 3;
      float v;
      if (n < 3)
        v = Cl[p][m*4+0]*Rl[i][0*3+n] + Cl[p][m*4+1]*Rl[i][1*3+n] + Cl[p][m*4+2]*Rl[i][2*3+n];
      else {
        float r0 = Jl[i][0]-Jl[p][0], r1 = Jl[i][1]-Jl[p][1], r2 = Jl[i][2]-Jl[p][2];
        v = Cl[p][m*4+0]*r0 + Cl[p][m*4+1]*r1 + Cl[p][m*4+2]*r2 + Cl[p][m*4+3];
      }
      Cl[i][t] = v;
    }
    __syncthreads();
  }
  if (t < 72) {
    int j = t / 3, c = t % 3;
    joints_out[(size_t)b*72 + t] = Cl[j][c*4+3] - Cl[0][c*4+3];
  }
  for (int idx = t; idx < 288; idx += 128) {
    int j = idx / 12, r = idx % 12, m = r >> 2, n = r & 3;
    float v;
    if (n < 3) v = Cl[j][m*4+n];
    else v = Cl[j][m*4+3] - (Cl[j][m*4+0]*Jl[j][0] + Cl[j][m*4+1]*Jl[j][1] + Cl[j][m*4+2]*Jl[j][2]);
    A[(size_t)b*288 + idx] = v;
  }
  if (write_pfb && t < 112) {
    unsigned int val = (unsigned int)f2bf(pfl[2*t]) |
                       ((unsigned int)f2bf(pfl[2*t+1]) << 16);
    ((unsigned int*)(pfb + (size_t)b * KP))[t] = val;
  }
}

// K_cvt: pdt local rows [0,CH) = global comps [C0, C0+CH): bf16 [n][k] with
// k<207 -> posedirs[k][n]; 207..216 -> shapedirs l; else 0.
#define VTC 64
__global__ __launch_bounds__(256) void k_cvt(const float* __restrict__ pd,
    const float* __restrict__ sd, unsigned short* __restrict__ pdt, int C0) {
  __shared__ unsigned short tt[VTC][KP + 8];
  int l0 = blockIdx.x * VTC;
  int n0 = C0 + l0;
  for (int i = threadIdx.x; i < VTC * (KP + 8) / 2; i += 256)
    ((unsigned int*)tt)[i] = 0u;
  __syncthreads();
  for (int idx = threadIdx.x; idx < NP * VTC; idx += 256) {
    int k = idx >> 6, n = idx & 63;
    int g = n0 + n;
    float v = (g < NV * 3) ? pd[(size_t)k * (NV * 3) + g] : 0.f;
    tt[n][k] = f2bf(v);
  }
  for (int idx = threadIdx.x; idx < 10 * VTC; idx += 256) {
    int n = idx / 10, l = idx % 10;
    int g = n0 + n;
    float v = 0.f;
    if (g < NV * 3) { int vv = g / 3, c = g % 3; v = sd[(size_t)vv * 30 + c * 10 + l]; }
    tt[n][NP + l] = f2bf(v);
  }
  __syncthreads();
  for (int i = threadIdx.x; i < VTC * (KP / 2); i += 256) {
    int row = i / (KP / 2), col = i % (KP / 2);
    unsigned int val = ((unsigned int)tt[row][2 * col]) |
                       (((unsigned int)tt[row][2 * col + 1]) << 16);
    ((unsigned int*)pdt)[(size_t)(l0 + row) * (KP / 2) + col] = val;
  }
}

// K2a: fused MFMA pose-GEMM + fp32 LBS. Block: 16 batches x 256 verts, 4 waves.
// vp staged as bf16 [768 comps][VPS u16] (transposed), unioned with pf staging
// -> 30,720 B LDS -> 5 blocks/CU.
__global__ __launch_bounds__(256, 5) void k_fused(
    const unsigned short* __restrict__ pfb,   // [B][224] bf16
    const unsigned short* __restrict__ pdt,   // [CH][224] bf16 (local rows)
    const float* __restrict__ A,              // [B][288] f32
    const float* __restrict__ w,              // [NV][24]
    const float* __restrict__ vtm,            // [NV][3]
    float* __restrict__ verts, int C0) {
  int b0 = blockIdx.x * BT;
  int lr0 = blockIdx.y * (VTB * 3);       // local pdt row base
  int v0 = C0 / 3 + blockIdx.y * VTB;     // global vertex base
  int t = threadIdx.x;
  int lane = t & 63;
  int wv = t >> 6;

  __shared__ unsigned long long smraw[768 * VPS / 4];   // 30,720 B (union)
  unsigned int* pfA = (unsigned int*)smraw;             // [16][116] dwords (7,424 B)
  unsigned short* vpb = (unsigned short*)smraw;         // [768][VPS] u16

  { // stage pf rows b0..b0+15 (contiguous 1792 dwords) into padded LDS
    const unsigned int* src = (const unsigned int*)(pfb + (size_t)b0 * KP);
#pragma unroll
    for (int i = 0; i < 7; i++) {
      int d = t + i * 256;
      pfA[(d / 112) * 116 + (d % 112)] = src[d];
    }
  }
  __syncthreads();

  // ---- phase 1: MFMA. wave wv covers comps [wv*192, wv*192+192) ----
  int q = lane >> 4;       // k-chunk selector / batch-group
  int m = lane & 15;       // A row (batch) / B row (comp)
  s8v af[7];
  {
    const unsigned int* arow = pfA + m * 116 + q * 4;
#pragma unroll
    for (int ks = 0; ks < 7; ks++) af[ks] = *(const s8v*)(arow + ks * 16);
  }
  __syncthreads();   // pfA dead; vpb region now writable

  const unsigned short* browb = pdt + (size_t)(lr0 + wv * 192 + m) * KP + q * 8;
#pragma unroll 1
  for (int f = 0; f < 12; f++) {
    const unsigned short* br = browb + (size_t)f * 16 * KP;
    f4v acc = {0.f, 0.f, 0.f, 0.f};
#pragma unroll
    for (int ks = 0; ks < 7; ks++)
      acc = __builtin_amdgcn_mfma_f32_16x16x32_bf16(af[ks], *(const s8v*)(br + ks * 32), acc, 0, 0, 0);
    // C/D layout (HW-validated): comp col = m, batch row = q*4 + r
    int comp = wv * 192 + f * 16 + m;
    unsigned int lo = (unsigned int)f2bf(acc[0]) | ((unsigned int)f2bf(acc[1]) << 16);
    unsigned int hi = (unsigned int)f2bf(acc[2]) | ((unsigned int)f2bf(acc[3]) << 16);
    *(unsigned long long*)(vpb + comp * VPS + q * 4) =
        (unsigned long long)lo | ((unsigned long long)hi << 32);
  }
  __syncthreads();

  // ---- phase 2: LBS epilogue (thread = vertex) ----
  int vglob = v0 + t;
  bool valid = vglob < NV;
  int vc = valid ? vglob : NV - 1;
  float wr[24];
  {
    const fx4* w4 = (const fx4*)(w + (size_t)vc * 24);
#pragma unroll
    for (int k = 0; k < 6; k++) {
      fx4 t4 = w4[k];
      wr[4*k]=t4.x; wr[4*k+1]=t4.y; wr[4*k+2]=t4.z; wr[4*k+3]=t4.w;
    }
  }
  float vt0 = vtm[(size_t)vc*3+0], vt1 = vtm[(size_t)vc*3+1], vt2 = vtm[(size_t)vc*3+2];

#pragma unroll 1
  for (int ib = 0; ib < BT; ib++) {
    const float* Ab = A + (size_t)(b0 + ib) * 288;
    float T[12];
#pragma unroll
    for (int r = 0; r < 12; r++) T[r] = 0.f;
#pragma unroll
    for (int j = 0; j < 24; j++) {
      float wj = wr[j];
      const fx4* a4 = (const fx4*)(Ab + j * 12);
      fx4 qa = a4[0], qb = a4[1], qc = a4[2];
      T[0]+=wj*qa.x; T[1]+=wj*qa.y; T[2]+=wj*qa.z;  T[3]+=wj*qa.w;
      T[4]+=wj*qb.x; T[5]+=wj*qb.y; T[6]+=wj*qb.z;  T[7]+=wj*qb.w;
      T[8]+=wj*qc.x; T[9]+=wj*qc.y; T[10]+=wj*qc.z; T[11]+=wj*qc.w;
    }
    unsigned int u0 = vpb[(t*3+0) * VPS + ib];
    unsigned int u1 = vpb[(t*3+1) * VPS + ib];
    unsigned int u2 = vpb[(t*3+2) * VPS + ib];
    float px = __builtin_bit_cast(float, u0 << 16) + vt0;
    float py = __builtin_bit_cast(float, u1 << 16) + vt1;
    float pz = __builtin_bit_cast(float, u2 << 16) + vt2;
    float o0 = T[0]*px + T[1]*py + T[2]*pz  + T[3];
    float o1 = T[4]*px + T[5]*py + T[6]*pz  + T[7];
    float o2 = T[8]*px + T[9]*py + T[10]*pz + T[11];
    if (valid) {
      float* dst = verts + ((size_t)(b0 + ib) * NV + vglob) * 3;
      dst[0] = o0; dst[1] = o1; dst[2] = o2;
    }
  }
}

// K2b: fp32 fallback (round-3 verified). thread = vertex, block covers 16 batches.
__global__ __launch_bounds__(256) void k_verts(
    const float* __restrict__ betas, const float* __restrict__ vt,
    const float* __restrict__ sd, const float* __restrict__ pd,
    const float* __restrict__ w, const float* __restrict__ pf,
    const float* __restrict__ A, float* __restrict__ verts) {
  int vbase = blockIdx.y * 256;
  int vraw = vbase + threadIdx.x;
  bool valid = vraw < NV;
  int v = valid ? vraw : (NV - 1);
  int b0 = blockIdx.x * BT;

  float sdr[30];
  {
    const fx2* s2 = (const fx2*)(sd + (size_t)v * 30);
#pragma unroll
    for (int q = 0; q < 15; q++) { fx2 tv = s2[q]; sdr[2*q] = tv.x; sdr[2*q+1] = tv.y; }
  }
  float vt0 = vt[(size_t)v*3+0], vt1 = vt[(size_t)v*3+1], vt2 = vt[(size_t)v*3+2];

  float acc[BT][3];
#pragma unroll
  for (int i = 0; i < BT; i++) {
    const float* be = betas + (size_t)(b0 + i) * 10;
    float a0 = vt0, a1 = vt1, a2 = vt2;
#pragma unroll
    for (int l = 0; l < 10; l++) {
      float bl = be[l];
      a0 += bl * sdr[l]; a1 += bl * sdr[10+l]; a2 += bl * sdr[20+l];
    }
    acc[i][0] = a0; acc[i][1] = a1; acc[i][2] = a2;
  }

  const float* pcol = pd + 3 * (size_t)v;
  float cur[12], nxt[12];
#pragma unroll
  for (int r = 0; r < 4; r++) {
    const float* rp = pcol + (size_t)r * 20670;
    cur[3*r] = rp[0]; cur[3*r+1] = rp[1]; cur[3*r+2] = rp[2];
  }
#pragma unroll 1
  for (int k = 0; k < 204; k += 4) {
    if (k < 200) {
#pragma unroll
      for (int r = 0; r < 4; r++) {
        const float* rp = pcol + (size_t)(k + 4 + r) * 20670;
        nxt[3*r] = rp[0]; nxt[3*r+1] = rp[1]; nxt[3*r+2] = rp[2];
      }
    }
#pragma unroll
    for (int i = 0; i < BT; i++) {
      fx4 q = *(const fx4*)(pf + (size_t)(b0 + i) * 208 + k);
      acc[i][0] += q.x*cur[0] + q.y*cur[3] + q.z*cur[6] + q.w*cur[9];
      acc[i][1] += q.x*cur[1] + q.y*cur[4] + q.z*cur[7] + q.w*cur[10];
      acc[i][2] += q.x*cur[2] + q.y*cur[5] + q.z*cur[8] + q.w*cur[11];
    }
#pragma unroll
    for (int r = 0; r < 12; r++) cur[r] = nxt[r];
  }
  {
    float p00,p01,p02,p10,p11,p12,p20,p21,p22;
    { const float* r = pcol + (size_t)204*20670; p00=r[0]; p01=r[1]; p02=r[2]; }
    { const float* r = pcol + (size_t)205*20670; p10=r[0]; p11=r[1]; p12=r[2]; }
    { const float* r = pcol + (size_t)206*20670; p20=r[0]; p21=r[1]; p22=r[2]; }
#pragma unroll
    for (int i = 0; i < BT; i++) {
      const float* pb = pf + (size_t)(b0 + i) * 208;
      float q0 = pb[204], q1 = pb[205], q2 = pb[206];
      acc[i][0] += q0*p00 + q1*p10 + q2*p20;
      acc[i][1] += q0*p01 + q1*p11 + q2*p21;
      acc[i][2] += q0*p02 + q1*p12 + q2*p22;
    }
  }

  float wr[24];
  {
    const fx4* w4 = (const fx4*)(w + (size_t)v * 24);
#pragma unroll
    for (int q = 0; q < 6; q++) {
      fx4 t4 = w4[q];
      wr[4*q]=t4.x; wr[4*q+1]=t4.y; wr[4*q+2]=t4.z; wr[4*q+3]=t4.w;
    }
  }

#pragma unroll 1
  for (int i = 0; i < BT; i++) {
    const float* Ab = A + (size_t)(b0 + i) * 288;
    float T[12];
#pragma unroll
    for (int q = 0; q < 12; q++) T[q] = 0.f;
#pragma unroll
    for (int j = 0; j < 24; j++) {
      float wj = wr[j];
      const fx4* a4 = (const fx4*)(Ab + j * 12);
      fx4 qa = a4[0], qb = a4[1], qc = a4[2];
      T[0]+=wj*qa.x; T[1]+=wj*qa.y; T[2]+=wj*qa.z;  T[3]+=wj*qa.w;
      T[4]+=wj*qb.x; T[5]+=wj*qb.y; T[6]+=wj*qb.z;  T[7]+=wj*qb.w;
      T[8]+=wj*qc.x; T[9]+=wj*qc.y; T[10]+=wj*qc.z; T[11]+=wj*qc.w;
    }
    float x = acc[i][0], y = acc[i][1], z = acc[i][2];
    float o0 = T[0]*x + T[1]*y + T[2]*z  + T[3];
    float o1 = T[4]*x + T[5]*y + T[6]*z  + T[7];
    float o2 = T[8]*x + T[9]*y + T[10]*z + T[11];
    if (valid) {
      float* dst = verts + ((size_t)(b0 + i) * NV + vraw) * 3;
      dst[0] = o0; dst[1] = o1; dst[2] = o2;
    }
  }
}

// K3: j17 from unshifted verts; write shifted j17; shift verts in place (fx2).
__global__ __launch_bounds__(256) void k_j17s(const float* __restrict__ jrh,
    float* __restrict__ verts, float* __restrict__ j17_out) {
  int b = blockIdx.x;
  float acc[17][3];
#pragma unroll
  for (int j = 0; j < 17; j++) { acc[j][0]=0.f; acc[j][1]=0.f; acc[j][2]=0.f; }
  float* vb = verts + (size_t)b * NV * 3;
  for (int v = threadIdx.x; v < NV; v += 256) {
    float x = vb[v*3], y = vb[v*3+1], z = vb[v*3+2];
#pragma unroll
    for (int j = 0; j < 17; j++) {
      float r = jrh[(size_t)j * NV + v];
      acc[j][0] += r*x; acc[j][1] += r*y; acc[j][2] += r*z;
    }
  }
#pragma unroll
  for (int j = 0; j < 17; j++) {
#pragma unroll
    for (int c = 0; c < 3; c++) {
      for (int off = 32; off; off >>= 1) acc[j][c] += __shfl_xor(acc[j][c], off, 64);
    }
  }
  __shared__ float red[4][51];
  __shared__ float fin[51];
  int wave = threadIdx.x >> 6, lane = threadIdx.x & 63;
  if (lane == 0) {
#pragma unroll
    for (int j = 0; j < 17; j++) {
      red[wave][j*3+0] = acc[j][0]; red[wave][j*3+1] = acc[j][1]; red[wave][j*3+2] = acc[j][2];
    }
  }
  __syncthreads();
  if (threadIdx.x < 51)
    fin[threadIdx.x] = red[0][threadIdx.x] + red[1][threadIdx.x] + red[2][threadIdx.x] + red[3][threadIdx.x];
  __syncthreads();
  if (threadIdx.x < 51) {
    int c = threadIdx.x % 3;
    j17_out[(size_t)b*51 + threadIdx.x] = fin[threadIdx.x] - fin[c];
  }
  float r0 = fin[0], r1 = fin[1], r2 = fin[2];
  // shift loop: fx2 RMW (NV*3 = 20670 floats = 10335 fx2, row start 8B-aligned)
  fx2* vb2 = (fx2*)vb;
  for (int idx = threadIdx.x; idx < 10335; idx += 256) {
    int f0 = idx * 2;
    int c0 = f0 % 3;
    int c1 = c0 + 1; if (c1 == 3) c1 = 0;
    float s0 = (c0 == 0) ? r0 : ((c0 == 1) ? r1 : r2);
    float s1 = (c1 == 0) ? r0 : ((c1 == 1) ? r1 : r2);
    fx2 x = vb2[idx];
    x.x -= s0; x.y -= s1;
    vb2[idx] = x;
  }
}

extern "C" void kernel_launch(void* const* d_in, const int* in_sizes, int n_in,
                              void* d_out, int out_size, void* d_ws, size_t ws_size,
                              hipStream_t stream) {
  const float* pose  = (const float*)d_in[0];
  const float* betas = (const float*)d_in[1];
  const float* glob  = (const float*)d_in[2];
  const float* vtm   = (const float*)d_in[3];
  const float* sd    = (const float*)d_in[4];
  const float* pd    = (const float*)d_in[5];
  const float* JR    = (const float*)d_in[6];
  const float* JRh   = (const float*)d_in[7];
  const float* w     = (const float*)d_in[8];
  float* out = (float*)d_out;
  char* wsb = (char*)d_ws;
  float* A             = (float*)(wsb + WSB_A);
  float* JRX           = (float*)(wsb + WSB_JRX);
  float* pf32          = (float*)(wsb + WSB_PF32);
  unsigned short* pfb  = (unsigned short*)(wsb + WSB_PFB);
  unsigned short* pdt  = (unsigned short*)(wsb + WSB_PDT);

  // ws tiers (chunks multiple of 768 rows). nch=1 proven available (round 7).
  int nch;
  if      (ws_size >= (size_t)2494464 + (size_t)NR * 448)        nch = 1;  // 11,784,192
  else if (ws_size >= (size_t)2494464 + (size_t)(NR/3) * 448)    nch = 3;  //  5,591,040
  else                                                           nch = 0;  // fp32 fallback

  k_jrx<<<72, 256, 0, stream>>>(JR, vtm, sd, JRX);
  k_pose<<<B, 128, 0, stream>>>(glob, pose, betas, JRX, out + OFF_R, out + OFF_J,
                                pf32, pfb, A, nch ? 1 : 0);
  if (nch) {
    int CH = NR / nch;                       // rows per chunk (mult of 768)
    for (int c = 0; c < nch; c++) {
      k_cvt<<<CH / VTC, 256, 0, stream>>>(pd, sd, pdt, c * CH);
      k_fused<<<dim3(B / BT, CH / (VTB * 3)), 256, 0, stream>>>(pfb, pdt, A, w, vtm,
                                                                out, c * CH);
    }
  } else {
    k_verts<<<dim3(B / BT, 27), 256, 0, stream>>>(betas, vtm, sd, pd, w, pf32, A, out);
  }
  k_j17s<<<B, 256, 0, stream>>>(JRh, out, out + OFF_J17);
}